// Round 2
// baseline (606.678 us; speedup 1.0000x reference)
//
#include <hip/hip_runtime.h>
#include <hip/hip_bf16.h>
#include <cmath>

#define C_DIM 768
#define E_DIM 8
#define H_DIM 3072

typedef short s16x8 __attribute__((ext_vector_type(8)));
typedef short s16x4 __attribute__((ext_vector_type(4)));
typedef float f32x4 __attribute__((ext_vector_type(4)));

__device__ __forceinline__ float bf2f(unsigned short u) {
  unsigned int v = ((unsigned int)u) << 16;
  float f;
  __builtin_memcpy(&f, &v, 4);
  return f;
}

__device__ __forceinline__ unsigned short f2bf(float f) {
  __hip_bfloat16 h = __float2bfloat16(f);
  unsigned short u;
  __builtin_memcpy(&u, &h, 2);
  return u;
}

// ---------------- K0: fp32 -> bf16 bulk convert (grid-stride, float4) ----------------
__global__ void cvt_kernel(const float* __restrict__ in, unsigned short* __restrict__ out, int n4) {
  int i = blockIdx.x * blockDim.x + threadIdx.x;
  const int stride = gridDim.x * blockDim.x;
  for (; i < n4; i += stride) {
    const float4 v = ((const float4*)in)[i];
    s16x4 p;
    p[0] = (short)f2bf(v.x);
    p[1] = (short)f2bf(v.y);
    p[2] = (short)f2bf(v.z);
    p[3] = (short)f2bf(v.w);
    *(s16x4*)(out + (size_t)i * 4) = p;
  }
}

// ---------------- K1: router (one wave per token, fp32) ----------------
__global__ void router_kernel(const float* __restrict__ x,
                              const float* __restrict__ w_r,
                              int* __restrict__ counts,
                              int* __restrict__ tok_e,
                              float* __restrict__ tok_p) {
  const int t = blockIdx.x;
  const int lane = threadIdx.x;  // 64
  float acc[E_DIM];
#pragma unroll
  for (int e = 0; e < E_DIM; ++e) acc[e] = 0.f;
  for (int c = lane; c < C_DIM; c += 64) {
    const float xv = x[(size_t)t * C_DIM + c];
    const float4 w0 = *(const float4*)(w_r + (size_t)c * E_DIM);
    const float4 w1 = *(const float4*)(w_r + (size_t)c * E_DIM + 4);
    acc[0] += xv * w0.x; acc[1] += xv * w0.y; acc[2] += xv * w0.z; acc[3] += xv * w0.w;
    acc[4] += xv * w1.x; acc[5] += xv * w1.y; acc[6] += xv * w1.z; acc[7] += xv * w1.w;
  }
#pragma unroll
  for (int e = 0; e < E_DIM; ++e) {
#pragma unroll
    for (int off = 32; off > 0; off >>= 1) acc[e] += __shfl_xor(acc[e], off, 64);
  }
  if (lane == 0) {
    int i0 = 0;
#pragma unroll
    for (int e = 1; e < E_DIM; ++e)
      if (acc[e] > acc[i0]) i0 = e;   // strict > : lowest index on tie (matches jax top_k)
    int i1 = (i0 == 0) ? 1 : 0;
#pragma unroll
    for (int e = 0; e < E_DIM; ++e)
      if (e != i0 && acc[e] > acc[i1]) i1 = e;
    const float d = expf(acc[i1] - acc[i0]);  // <= 1
    const float p0 = 1.f / (1.f + d);
    tok_e[2 * t] = i0;
    tok_e[2 * t + 1] = i1;
    tok_p[2 * t] = p0;
    tok_p[2 * t + 1] = 1.f - p0;
    atomicAdd(counts + i0, 1);
    atomicAdd(counts + i1, 1);
  }
}

// ---------------- K2: schedule (single thread; 8 experts) ----------------
__global__ void schedule_kernel(const int* __restrict__ counts,
                                int* __restrict__ pad_off,
                                int* __restrict__ table_e,
                                int* __restrict__ table_row,
                                int tableCap) {
  if (threadIdx.x != 0) return;
  int running = 0, idx = 0;
  for (int e = 0; e < E_DIM; ++e) {
    pad_off[e] = running;
    const int tiles = (counts[e] + 127) >> 7;  // 128-row tiles
    for (int j = 0; j < tiles && idx < tableCap; ++j) {
      table_e[idx] = e;
      table_row[idx] = running + j * 128;
      ++idx;
    }
    running += tiles << 7;
  }
  for (; idx < tableCap; ++idx) table_e[idx] = -1;
}

// ---------------- K3: slot assignment + gather rows (fp32 x -> bf16 Xg) ----------------
__global__ void gather_kernel(const float* __restrict__ x,
                              const int* __restrict__ tok_e,
                              const int* __restrict__ pad_off,
                              int* __restrict__ cursors,
                              int* __restrict__ tok_slot,
                              unsigned short* __restrict__ Xg) {
  const int t = blockIdx.x;
  const int lane = threadIdx.x;  // 64
  __shared__ int slots[2];
  if (lane < 2) {
    const int e = tok_e[2 * t + lane];
    const int s = pad_off[e] + atomicAdd(cursors + e, 1);
    tok_slot[2 * t + lane] = s;
    slots[lane] = s;
  }
  __syncthreads();
  const float4* src = (const float4*)(x + (size_t)t * C_DIM);  // 192 x 16B
  // convert once into registers, write to both slots
  for (int q = lane; q < C_DIM / 4; q += 64) {
    const float4 v = src[q];
    s16x4 p;
    p[0] = (short)f2bf(v.x);
    p[1] = (short)f2bf(v.y);
    p[2] = (short)f2bf(v.z);
    p[3] = (short)f2bf(v.w);
    *(s16x4*)(Xg + (size_t)slots[0] * C_DIM + q * 4) = p;
    *(s16x4*)(Xg + (size_t)slots[1] * C_DIM + q * 4) = p;
  }
}

// ---------------- K4: fused fc + gate GEMM + SwiGLU -> act (bf16) ----------------
// Block tile 128(M) x 64(N), BK=32. 4 waves in 2x2; wave tile 64x32 = 4x2 mfma16 tiles.
__global__ __launch_bounds__(256, 2) void fcgate_kernel(
    const unsigned short* __restrict__ Xg, const unsigned short* __restrict__ w_fc,
    const float* __restrict__ b_fc, const unsigned short* __restrict__ w_gt,
    const float* __restrict__ b_gt, const int* __restrict__ table_e,
    const int* __restrict__ table_row, unsigned short* __restrict__ act) {
  const int mt = blockIdx.y;
  const int e = table_e[mt];
  if (e < 0) return;
  const int row0 = table_row[mt];
  const int nt = blockIdx.x;  // 0..47
  const int tid = threadIdx.x;
  const int lane = tid & 63;
  const int wid = tid >> 6;
  const int quad = lane >> 4;
  const int l16 = lane & 15;
  const int wrow = (wid >> 1) * 64;  // 0/64
  const int wcol = (wid & 1) * 32;   // 0/32

  __shared__ unsigned short As[128 * 40];    // [m][k], stride 40 (16B-aligned rows)
  __shared__ unsigned short Bs[2][32 * 72];  // [k][n], stride 72, quad-rotated cols

  const unsigned short* wptr[2];
  wptr[0] = w_fc + (size_t)e * C_DIM * H_DIM + nt * 64;
  wptr[1] = w_gt + (size_t)e * C_DIM * H_DIM + nt * 64;

  f32x4 accH[4][2], accG[4][2];
#pragma unroll
  for (int i = 0; i < 4; ++i)
#pragma unroll
    for (int j = 0; j < 2; ++j)
#pragma unroll
      for (int r = 0; r < 4; ++r) {
        accH[i][j][r] = 0.f;
        accG[i][j][r] = 0.f;
      }

  const int ar = tid >> 1;        // 0..127
  const int ac = (tid & 1) * 16;  // 0/16
  const int bk = tid >> 3;        // 0..31
  const int bn = (tid & 7) * 8;   // 0..56
  const int bcol = (bn + ((bk >> 3) << 4)) & 63;  // rotate by k-quad*16

  for (int k0 = 0; k0 < C_DIM; k0 += 32) {
    const uint4 av0 = *(const uint4*)(Xg + (size_t)(row0 + ar) * C_DIM + k0 + ac);
    const uint4 av1 = *(const uint4*)(Xg + (size_t)(row0 + ar) * C_DIM + k0 + ac + 8);
    const uint4 bv0 = *(const uint4*)(wptr[0] + (size_t)(k0 + bk) * H_DIM + bn);
    const uint4 bv1 = *(const uint4*)(wptr[1] + (size_t)(k0 + bk) * H_DIM + bn);
    __syncthreads();
    *(uint4*)(&As[ar * 40 + ac]) = av0;
    *(uint4*)(&As[ar * 40 + ac + 8]) = av1;
    *(uint4*)(&Bs[0][bk * 72 + bcol]) = bv0;
    *(uint4*)(&Bs[1][bk * 72 + bcol]) = bv1;
    __syncthreads();

    s16x8 afrag[4];
#pragma unroll
    for (int tr = 0; tr < 4; ++tr)
      afrag[tr] = *(const s16x8*)(&As[(wrow + tr * 16 + l16) * 40 + quad * 8]);

#pragma unroll
    for (int tc = 0; tc < 2; ++tc) {
      const int nn = wcol + tc * 16 + l16;
      const int ncol = (nn + (quad << 4)) & 63;  // same rotation as writes
      s16x8 bF, bG;
#pragma unroll
      for (int j = 0; j < 8; ++j) {
        bF[j] = (short)Bs[0][(quad * 8 + j) * 72 + ncol];
        bG[j] = (short)Bs[1][(quad * 8 + j) * 72 + ncol];
      }
#pragma unroll
      for (int tr = 0; tr < 4; ++tr) {
        accH[tr][tc] = __builtin_amdgcn_mfma_f32_16x16x32_bf16(afrag[tr], bF, accH[tr][tc], 0, 0, 0);
        accG[tr][tc] = __builtin_amdgcn_mfma_f32_16x16x32_bf16(afrag[tr], bG, accG[tr][tc], 0, 0, 0);
      }
    }
  }

  // epilogue: act = (h + b_fc) * silu(g + b_gt)
#pragma unroll
  for (int tc = 0; tc < 2; ++tc) {
    const int col = nt * 64 + wcol + tc * 16 + l16;
    const float bf = b_fc[e * H_DIM + col];
    const float bg = b_gt[e * H_DIM + col];
#pragma unroll
    for (int tr = 0; tr < 4; ++tr) {
#pragma unroll
      for (int r = 0; r < 4; ++r) {
        const int row = row0 + wrow + tr * 16 + quad * 4 + r;  // C/D: row=quad*4+reg, col=l16
        const float hv = accH[tr][tc][r] + bf;
        const float gv = accG[tr][tc][r] + bg;
        const float sv = gv / (1.f + __expf(-gv));
        act[(size_t)row * H_DIM + col] = f2bf(hv * sv);
      }
    }
  }
}

// ---------------- K5: proj GEMM -> o (fp32) ----------------
__global__ __launch_bounds__(256, 2) void proj_kernel(
    const unsigned short* __restrict__ act, const unsigned short* __restrict__ w_pj,
    const float* __restrict__ b_pj, const int* __restrict__ table_e,
    const int* __restrict__ table_row, float* __restrict__ o) {
  const int mt = blockIdx.y;
  const int e = table_e[mt];
  if (e < 0) return;
  const int row0 = table_row[mt];
  const int nt = blockIdx.x;  // 0..11
  const int tid = threadIdx.x;
  const int lane = tid & 63;
  const int wid = tid >> 6;
  const int quad = lane >> 4;
  const int l16 = lane & 15;
  const int wrow = (wid >> 1) * 64;
  const int wcol = (wid & 1) * 32;

  __shared__ unsigned short As[128 * 40];
  __shared__ unsigned short Bs[32 * 72];

  const unsigned short* wp = w_pj + (size_t)e * H_DIM * C_DIM + nt * 64;

  f32x4 acc[4][2];
#pragma unroll
  for (int i = 0; i < 4; ++i)
#pragma unroll
    for (int j = 0; j < 2; ++j)
#pragma unroll
      for (int r = 0; r < 4; ++r) acc[i][j][r] = 0.f;

  const int ar = tid >> 1;
  const int ac = (tid & 1) * 16;
  const int bk = tid >> 3;
  const int bn = (tid & 7) * 8;
  const int bcol = (bn + ((bk >> 3) << 4)) & 63;

  for (int k0 = 0; k0 < H_DIM; k0 += 32) {
    const uint4 av0 = *(const uint4*)(act + (size_t)(row0 + ar) * H_DIM + k0 + ac);
    const uint4 av1 = *(const uint4*)(act + (size_t)(row0 + ar) * H_DIM + k0 + ac + 8);
    const uint4 bv0 = *(const uint4*)(wp + (size_t)(k0 + bk) * C_DIM + bn);
    __syncthreads();
    *(uint4*)(&As[ar * 40 + ac]) = av0;
    *(uint4*)(&As[ar * 40 + ac + 8]) = av1;
    *(uint4*)(&Bs[bk * 72 + bcol]) = bv0;
    __syncthreads();

    s16x8 afrag[4];
#pragma unroll
    for (int tr = 0; tr < 4; ++tr)
      afrag[tr] = *(const s16x8*)(&As[(wrow + tr * 16 + l16) * 40 + quad * 8]);

#pragma unroll
    for (int tc = 0; tc < 2; ++tc) {
      const int nn = wcol + tc * 16 + l16;
      const int ncol = (nn + (quad << 4)) & 63;
      s16x8 bB;
#pragma unroll
      for (int j = 0; j < 8; ++j) bB[j] = (short)Bs[(quad * 8 + j) * 72 + ncol];
#pragma unroll
      for (int tr = 0; tr < 4; ++tr)
        acc[tr][tc] = __builtin_amdgcn_mfma_f32_16x16x32_bf16(afrag[tr], bB, acc[tr][tc], 0, 0, 0);
    }
  }

#pragma unroll
  for (int tc = 0; tc < 2; ++tc) {
    const int col = nt * 64 + wcol + tc * 16 + l16;
    const float bp = b_pj[e * C_DIM + col];
#pragma unroll
    for (int tr = 0; tr < 4; ++tr) {
#pragma unroll
      for (int r = 0; r < 4; ++r) {
        const int row = row0 + wrow + tr * 16 + quad * 4 + r;
        o[(size_t)row * C_DIM + col] = acc[tr][tc][r] + bp;
      }
    }
  }
}

// ---------------- K6: combine -> fp32 out ----------------
__global__ void combine_kernel(const float* __restrict__ o,
                               const int* __restrict__ tok_slot,
                               const float* __restrict__ tok_p,
                               float* __restrict__ out) {
  const int t = blockIdx.x;
  const int lane = threadIdx.x;  // 64
  const int s0 = tok_slot[2 * t], s1 = tok_slot[2 * t + 1];
  const float p0 = tok_p[2 * t], p1 = tok_p[2 * t + 1];
  const f32x4* r0 = (const f32x4*)(o + (size_t)s0 * C_DIM);
  const f32x4* r1 = (const f32x4*)(o + (size_t)s1 * C_DIM);
  f32x4* dst = (f32x4*)(out + (size_t)t * C_DIM);
  for (int q = lane; q < C_DIM / 4; q += 64) {
    const f32x4 a = r0[q];
    const f32x4 b = r1[q];
    dst[q] = a * p0 + b * p1;
  }
}

extern "C" void kernel_launch(void* const* d_in, const int* in_sizes, int n_in,
                              void* d_out, int out_size, void* d_ws, size_t ws_size,
                              hipStream_t stream) {
  const int N = in_sizes[0] / C_DIM;  // 2048 tokens
  char* ws = (char*)d_ws;

  int* counts = (int*)(ws + 0);     // 8
  int* cursors = (int*)(ws + 32);   // 8
  int* pad_off = (int*)(ws + 64);   // 8
  int* table_e = (int*)(ws + 128);  // up to 64
  int* table_row = (int*)(ws + 384);
  int* tok_e = (int*)(ws + 1024);
  float* tok_p = (float*)(ws + 1024 + (size_t)8 * N);
  int* tok_slot = (int*)(ws + 1024 + (size_t)16 * N);

  int tableCap = (2 * N) / 128 + E_DIM;  // 40 for N=2048 (>= max possible tiles)
  if (tableCap > 64) tableCap = 64;

  size_t off = 1024 + (size_t)24 * N;
  off = (off + 255) & ~(size_t)255;
  const size_t R = (size_t)2 * N + 128 * E_DIM;  // padded-row allocation (5120)
  unsigned short* Xg = (unsigned short*)(ws + off);
  const size_t xg_bytes = R * C_DIM * 2;

  const size_t wbytes = (size_t)E_DIM * C_DIM * H_DIM * 2;  // 37.75 MB each (bf16)
  size_t wfc_off = (off + xg_bytes + 255) & ~(size_t)255;
  size_t wgt_off = wfc_off + wbytes;
  size_t wpj_off = wgt_off + wbytes;
  unsigned short* wfc_bf = (unsigned short*)(ws + wfc_off);
  unsigned short* wgt_bf = (unsigned short*)(ws + wgt_off);
  unsigned short* wpj_bf = (unsigned short*)(ws + wpj_off);

  size_t act_off = (wpj_off + wbytes + 255) & ~(size_t)255;
  unsigned short* act = (unsigned short*)(ws + act_off);
  size_t o_off = (act_off + R * H_DIM * 2 + 255) & ~(size_t)255;
  float* o = (float*)(ws + o_off);
  const size_t need = o_off + R * C_DIM * 4;
  if (ws_size < need || n_in < 9) return;  // scratch too small: bail cleanly

  hipMemsetAsync(ws, 0, 1024, stream);      // counts/cursors/tables
  hipMemsetAsync(Xg, 0, xg_bytes, stream);  // zero pad rows

  const int WN4 = (int)(E_DIM * C_DIM * H_DIM / 4);
  cvt_kernel<<<4096, 256, 0, stream>>>((const float*)d_in[2], wfc_bf, WN4);
  cvt_kernel<<<4096, 256, 0, stream>>>((const float*)d_in[4], wgt_bf, WN4);
  cvt_kernel<<<4096, 256, 0, stream>>>((const float*)d_in[6], wpj_bf, WN4);

  router_kernel<<<N, 64, 0, stream>>>((const float*)d_in[0], (const float*)d_in[1],
                                      counts, tok_e, tok_p);
  schedule_kernel<<<1, 64, 0, stream>>>(counts, pad_off, table_e, table_row, tableCap);
  gather_kernel<<<N, 64, 0, stream>>>((const float*)d_in[0], tok_e, pad_off,
                                      cursors, tok_slot, Xg);
  fcgate_kernel<<<dim3(H_DIM / 64, tableCap), 256, 0, stream>>>(
      Xg, wfc_bf, (const float*)d_in[3], wgt_bf, (const float*)d_in[5],
      table_e, table_row, act);
  proj_kernel<<<dim3(C_DIM / 64, tableCap), 256, 0, stream>>>(
      act, wpj_bf, (const float*)d_in[7], table_e, table_row, o);
  combine_kernel<<<N, 64, 0, stream>>>(o, tok_slot, tok_p, (float*)d_out);
}

// Round 3
// 421.622 us; speedup vs baseline: 1.4389x; 1.4389x over previous
//
#include <hip/hip_runtime.h>
#include <hip/hip_bf16.h>
#include <cmath>

#define C_DIM 768
#define E_DIM 8
#define H_DIM 3072
#define CNT_STRIDE 32  // ints; one 128B line per expert counter

typedef short s16x8 __attribute__((ext_vector_type(8)));
typedef short s16x4 __attribute__((ext_vector_type(4)));
typedef float f32x4 __attribute__((ext_vector_type(4)));

__device__ __forceinline__ float bf2f(unsigned short u) {
  unsigned int v = ((unsigned int)u) << 16;
  float f;
  __builtin_memcpy(&f, &v, 4);
  return f;
}

__device__ __forceinline__ unsigned short f2bf(float f) {
  __hip_bfloat16 h = __float2bfloat16(f);
  unsigned short u;
  __builtin_memcpy(&u, &h, 2);
  return u;
}

// ---------------- K0: fp32 -> bf16 bulk convert (grid-stride, float4) ----------------
__global__ void cvt_kernel(const float* __restrict__ in, unsigned short* __restrict__ out, int n4) {
  int i = blockIdx.x * blockDim.x + threadIdx.x;
  const int stride = gridDim.x * blockDim.x;
  for (; i < n4; i += stride) {
    const float4 v = ((const float4*)in)[i];
    s16x4 p;
    p[0] = (short)f2bf(v.x);
    p[1] = (short)f2bf(v.y);
    p[2] = (short)f2bf(v.z);
    p[3] = (short)f2bf(v.w);
    *(s16x4*)(out + (size_t)i * 4) = p;
  }
}

// ---------------- K1: router (one wave per token, fp32; NO atomics) ----------------
__global__ void router_kernel(const float* __restrict__ x,
                              const float* __restrict__ w_r,
                              int* __restrict__ tok_e,
                              float* __restrict__ tok_p) {
  const int t = blockIdx.x;
  const int lane = threadIdx.x;  // 64
  float acc[E_DIM];
#pragma unroll
  for (int e = 0; e < E_DIM; ++e) acc[e] = 0.f;
  for (int c = lane; c < C_DIM; c += 64) {
    const float xv = x[(size_t)t * C_DIM + c];
    const float4 w0 = *(const float4*)(w_r + (size_t)c * E_DIM);
    const float4 w1 = *(const float4*)(w_r + (size_t)c * E_DIM + 4);
    acc[0] += xv * w0.x; acc[1] += xv * w0.y; acc[2] += xv * w0.z; acc[3] += xv * w0.w;
    acc[4] += xv * w1.x; acc[5] += xv * w1.y; acc[6] += xv * w1.z; acc[7] += xv * w1.w;
  }
#pragma unroll
  for (int e = 0; e < E_DIM; ++e) {
#pragma unroll
    for (int off = 32; off > 0; off >>= 1) acc[e] += __shfl_xor(acc[e], off, 64);
  }
  if (lane == 0) {
    int i0 = 0;
#pragma unroll
    for (int e = 1; e < E_DIM; ++e)
      if (acc[e] > acc[i0]) i0 = e;   // strict > : lowest index on tie (matches jax top_k)
    int i1 = (i0 == 0) ? 1 : 0;
#pragma unroll
    for (int e = 0; e < E_DIM; ++e)
      if (e != i0 && acc[e] > acc[i1]) i1 = e;
    const float d = expf(acc[i1] - acc[i0]);  // <= 1
    const float p0 = 1.f / (1.f + d);
    tok_e[2 * t] = i0;
    tok_e[2 * t + 1] = i1;
    tok_p[2 * t] = p0;
    tok_p[2 * t + 1] = 1.f - p0;
  }
}

// ---------------- K1b: slot rank assignment (LDS-aggregated; 64 global atomics total) ----
__global__ void assign_kernel(const int* __restrict__ tok_e,
                              int* __restrict__ counts,     // strided CNT_STRIDE
                              int* __restrict__ tok_rank,
                              int N) {
  __shared__ int lcnt[E_DIM];
  __shared__ int lbase[E_DIM];
  const int tid = threadIdx.x;
  const int t = blockIdx.x * blockDim.x + tid;
  if (tid < E_DIM) lcnt[tid] = 0;
  __syncthreads();
  int e0 = 0, e1 = 0, r0 = 0, r1 = 0;
  const bool valid = (t < N);
  if (valid) {
    e0 = tok_e[2 * t];
    e1 = tok_e[2 * t + 1];
    r0 = atomicAdd(&lcnt[e0], 1);  // LDS atomic — on-CU, fast
    r1 = atomicAdd(&lcnt[e1], 1);
  }
  __syncthreads();
  if (tid < E_DIM) lbase[tid] = atomicAdd(counts + tid * CNT_STRIDE, lcnt[tid]);
  __syncthreads();
  if (valid) {
    tok_rank[2 * t] = lbase[e0] + r0;
    tok_rank[2 * t + 1] = lbase[e1] + r1;
  }
}

// ---------------- K2: schedule (single thread; 8 experts) ----------------
__global__ void schedule_kernel(const int* __restrict__ counts,
                                int* __restrict__ pad_off,
                                int* __restrict__ table_e,
                                int* __restrict__ table_row,
                                int tableCap) {
  if (threadIdx.x != 0) return;
  int running = 0, idx = 0;
  for (int e = 0; e < E_DIM; ++e) {
    pad_off[e] = running;
    const int tiles = (counts[e * CNT_STRIDE] + 127) >> 7;  // 128-row tiles
    for (int j = 0; j < tiles && idx < tableCap; ++j) {
      table_e[idx] = e;
      table_row[idx] = running + j * 128;
      ++idx;
    }
    running += tiles << 7;
  }
  for (; idx < tableCap; ++idx) table_e[idx] = -1;
}

// ---------------- K3: gather rows (fp32 x -> bf16 Xg; NO atomics) ----------------
__global__ void gather_kernel(const float* __restrict__ x,
                              const int* __restrict__ tok_e,
                              const int* __restrict__ tok_rank,
                              const int* __restrict__ pad_off,
                              int* __restrict__ tok_slot,
                              unsigned short* __restrict__ Xg) {
  const int t = blockIdx.x;
  const int lane = threadIdx.x;  // 64
  const int s0 = pad_off[tok_e[2 * t]] + tok_rank[2 * t];
  const int s1 = pad_off[tok_e[2 * t + 1]] + tok_rank[2 * t + 1];
  if (lane == 0) {
    tok_slot[2 * t] = s0;
    tok_slot[2 * t + 1] = s1;
  }
  const float4* src = (const float4*)(x + (size_t)t * C_DIM);  // 192 x 16B
  for (int q = lane; q < C_DIM / 4; q += 64) {
    const float4 v = src[q];
    s16x4 p;
    p[0] = (short)f2bf(v.x);
    p[1] = (short)f2bf(v.y);
    p[2] = (short)f2bf(v.z);
    p[3] = (short)f2bf(v.w);
    *(s16x4*)(Xg + (size_t)s0 * C_DIM + q * 4) = p;
    *(s16x4*)(Xg + (size_t)s1 * C_DIM + q * 4) = p;
  }
}

// ---------------- K4: fused fc + gate GEMM + SwiGLU -> act (bf16) ----------------
// Block tile 128(M) x 64(N), BK=32. 4 waves in 2x2; wave tile 64x32 = 4x2 mfma16 tiles.
__global__ __launch_bounds__(256, 2) void fcgate_kernel(
    const unsigned short* __restrict__ Xg, const unsigned short* __restrict__ w_fc,
    const float* __restrict__ b_fc, const unsigned short* __restrict__ w_gt,
    const float* __restrict__ b_gt, const int* __restrict__ table_e,
    const int* __restrict__ table_row, unsigned short* __restrict__ act) {
  const int mt = blockIdx.y;
  const int e = table_e[mt];
  if (e < 0) return;
  const int row0 = table_row[mt];
  const int nt = blockIdx.x;  // 0..47
  const int tid = threadIdx.x;
  const int lane = tid & 63;
  const int wid = tid >> 6;
  const int quad = lane >> 4;
  const int l16 = lane & 15;
  const int wrow = (wid >> 1) * 64;  // 0/64
  const int wcol = (wid & 1) * 32;   // 0/32

  __shared__ unsigned short As[128 * 40];    // [m][k], stride 40 (16B-aligned rows)
  __shared__ unsigned short Bs[2][32 * 72];  // [k][n], stride 72, quad-rotated cols

  const unsigned short* wptr[2];
  wptr[0] = w_fc + (size_t)e * C_DIM * H_DIM + nt * 64;
  wptr[1] = w_gt + (size_t)e * C_DIM * H_DIM + nt * 64;

  f32x4 accH[4][2], accG[4][2];
#pragma unroll
  for (int i = 0; i < 4; ++i)
#pragma unroll
    for (int j = 0; j < 2; ++j)
#pragma unroll
      for (int r = 0; r < 4; ++r) {
        accH[i][j][r] = 0.f;
        accG[i][j][r] = 0.f;
      }

  const int ar = tid >> 1;        // 0..127
  const int ac = (tid & 1) * 16;  // 0/16
  const int bk = tid >> 3;        // 0..31
  const int bn = (tid & 7) * 8;   // 0..56
  const int bcol = (bn + ((bk >> 3) << 4)) & 63;  // rotate by k-quad*16

  for (int k0 = 0; k0 < C_DIM; k0 += 32) {
    const uint4 av0 = *(const uint4*)(Xg + (size_t)(row0 + ar) * C_DIM + k0 + ac);
    const uint4 av1 = *(const uint4*)(Xg + (size_t)(row0 + ar) * C_DIM + k0 + ac + 8);
    const uint4 bv0 = *(const uint4*)(wptr[0] + (size_t)(k0 + bk) * H_DIM + bn);
    const uint4 bv1 = *(const uint4*)(wptr[1] + (size_t)(k0 + bk) * H_DIM + bn);
    __syncthreads();
    *(uint4*)(&As[ar * 40 + ac]) = av0;
    *(uint4*)(&As[ar * 40 + ac + 8]) = av1;
    *(uint4*)(&Bs[0][bk * 72 + bcol]) = bv0;
    *(uint4*)(&Bs[1][bk * 72 + bcol]) = bv1;
    __syncthreads();

    s16x8 afrag[4];
#pragma unroll
    for (int tr = 0; tr < 4; ++tr)
      afrag[tr] = *(const s16x8*)(&As[(wrow + tr * 16 + l16) * 40 + quad * 8]);

#pragma unroll
    for (int tc = 0; tc < 2; ++tc) {
      const int nn = wcol + tc * 16 + l16;
      const int ncol = (nn + (quad << 4)) & 63;  // same rotation as writes
      s16x8 bF, bG;
#pragma unroll
      for (int j = 0; j < 8; ++j) {
        bF[j] = (short)Bs[0][(quad * 8 + j) * 72 + ncol];
        bG[j] = (short)Bs[1][(quad * 8 + j) * 72 + ncol];
      }
#pragma unroll
      for (int tr = 0; tr < 4; ++tr) {
        accH[tr][tc] = __builtin_amdgcn_mfma_f32_16x16x32_bf16(afrag[tr], bF, accH[tr][tc], 0, 0, 0);
        accG[tr][tc] = __builtin_amdgcn_mfma_f32_16x16x32_bf16(afrag[tr], bG, accG[tr][tc], 0, 0, 0);
      }
    }
  }

  // epilogue: act = (h + b_fc) * silu(g + b_gt)
#pragma unroll
  for (int tc = 0; tc < 2; ++tc) {
    const int col = nt * 64 + wcol + tc * 16 + l16;
    const float bf = b_fc[e * H_DIM + col];
    const float bg = b_gt[e * H_DIM + col];
#pragma unroll
    for (int tr = 0; tr < 4; ++tr) {
#pragma unroll
      for (int r = 0; r < 4; ++r) {
        const int row = row0 + wrow + tr * 16 + quad * 4 + r;  // C/D: row=quad*4+reg, col=l16
        const float hv = accH[tr][tc][r] + bf;
        const float gv = accG[tr][tc][r] + bg;
        const float sv = gv / (1.f + __expf(-gv));
        act[(size_t)row * H_DIM + col] = f2bf(hv * sv);
      }
    }
  }
}

// ---------------- K5: proj GEMM -> o (fp32) ----------------
__global__ __launch_bounds__(256, 2) void proj_kernel(
    const unsigned short* __restrict__ act, const unsigned short* __restrict__ w_pj,
    const float* __restrict__ b_pj, const int* __restrict__ table_e,
    const int* __restrict__ table_row, float* __restrict__ o) {
  const int mt = blockIdx.y;
  const int e = table_e[mt];
  if (e < 0) return;
  const int row0 = table_row[mt];
  const int nt = blockIdx.x;  // 0..11
  const int tid = threadIdx.x;
  const int lane = tid & 63;
  const int wid = tid >> 6;
  const int quad = lane >> 4;
  const int l16 = lane & 15;
  const int wrow = (wid >> 1) * 64;
  const int wcol = (wid & 1) * 32;

  __shared__ unsigned short As[128 * 40];
  __shared__ unsigned short Bs[32 * 72];

  const unsigned short* wp = w_pj + (size_t)e * H_DIM * C_DIM + nt * 64;

  f32x4 acc[4][2];
#pragma unroll
  for (int i = 0; i < 4; ++i)
#pragma unroll
    for (int j = 0; j < 2; ++j)
#pragma unroll
      for (int r = 0; r < 4; ++r) acc[i][j][r] = 0.f;

  const int ar = tid >> 1;
  const int ac = (tid & 1) * 16;
  const int bk = tid >> 3;
  const int bn = (tid & 7) * 8;
  const int bcol = (bn + ((bk >> 3) << 4)) & 63;

  for (int k0 = 0; k0 < H_DIM; k0 += 32) {
    const uint4 av0 = *(const uint4*)(act + (size_t)(row0 + ar) * H_DIM + k0 + ac);
    const uint4 av1 = *(const uint4*)(act + (size_t)(row0 + ar) * H_DIM + k0 + ac + 8);
    const uint4 bv0 = *(const uint4*)(wp + (size_t)(k0 + bk) * C_DIM + bn);
    __syncthreads();
    *(uint4*)(&As[ar * 40 + ac]) = av0;
    *(uint4*)(&As[ar * 40 + ac + 8]) = av1;
    *(uint4*)(&Bs[bk * 72 + bcol]) = bv0;
    __syncthreads();

    s16x8 afrag[4];
#pragma unroll
    for (int tr = 0; tr < 4; ++tr)
      afrag[tr] = *(const s16x8*)(&As[(wrow + tr * 16 + l16) * 40 + quad * 8]);

#pragma unroll
    for (int tc = 0; tc < 2; ++tc) {
      const int nn = wcol + tc * 16 + l16;
      const int ncol = (nn + (quad << 4)) & 63;
      s16x8 bB;
#pragma unroll
      for (int j = 0; j < 8; ++j) bB[j] = (short)Bs[(quad * 8 + j) * 72 + ncol];
#pragma unroll
      for (int tr = 0; tr < 4; ++tr)
        acc[tr][tc] = __builtin_amdgcn_mfma_f32_16x16x32_bf16(afrag[tr], bB, acc[tr][tc], 0, 0, 0);
    }
  }

#pragma unroll
  for (int tc = 0; tc < 2; ++tc) {
    const int col = nt * 64 + wcol + tc * 16 + l16;
    const float bp = b_pj[e * C_DIM + col];
#pragma unroll
    for (int tr = 0; tr < 4; ++tr) {
#pragma unroll
      for (int r = 0; r < 4; ++r) {
        const int row = row0 + wrow + tr * 16 + quad * 4 + r;
        o[(size_t)row * C_DIM + col] = acc[tr][tc][r] + bp;
      }
    }
  }
}

// ---------------- K6: combine -> fp32 out ----------------
__global__ void combine_kernel(const float* __restrict__ o,
                               const int* __restrict__ tok_slot,
                               const float* __restrict__ tok_p,
                               float* __restrict__ out) {
  const int t = blockIdx.x;
  const int lane = threadIdx.x;  // 64
  const int s0 = tok_slot[2 * t], s1 = tok_slot[2 * t + 1];
  const float p0 = tok_p[2 * t], p1 = tok_p[2 * t + 1];
  const f32x4* r0 = (const f32x4*)(o + (size_t)s0 * C_DIM);
  const f32x4* r1 = (const f32x4*)(o + (size_t)s1 * C_DIM);
  f32x4* dst = (f32x4*)(out + (size_t)t * C_DIM);
  for (int q = lane; q < C_DIM / 4; q += 64) {
    const f32x4 a = r0[q];
    const f32x4 b = r1[q];
    dst[q] = a * p0 + b * p1;
  }
}

extern "C" void kernel_launch(void* const* d_in, const int* in_sizes, int n_in,
                              void* d_out, int out_size, void* d_ws, size_t ws_size,
                              hipStream_t stream) {
  const int N = in_sizes[0] / C_DIM;  // 2048 tokens
  char* ws = (char*)d_ws;

  int* counts = (int*)(ws + 0);       // 8 x CNT_STRIDE ints = 1024 B
  int* pad_off = (int*)(ws + 1024);   // 8 ints
  int* table_e = (int*)(ws + 1152);   // up to 64
  int* table_row = (int*)(ws + 1408);
  int* tok_e = (int*)(ws + 2048);
  float* tok_p = (float*)(ws + 2048 + (size_t)8 * N);
  int* tok_rank = (int*)(ws + 2048 + (size_t)16 * N);
  int* tok_slot = (int*)(ws + 2048 + (size_t)24 * N);

  int tableCap = (2 * N) / 128 + E_DIM;  // 40 for N=2048 (>= max possible tiles)
  if (tableCap > 64) tableCap = 64;

  size_t off = 2048 + (size_t)32 * N;
  off = (off + 255) & ~(size_t)255;
  const size_t R = (size_t)2 * N + 128 * E_DIM;  // padded-row allocation (5120)
  unsigned short* Xg = (unsigned short*)(ws + off);
  const size_t xg_bytes = R * C_DIM * 2;

  const size_t wbytes = (size_t)E_DIM * C_DIM * H_DIM * 2;  // 37.75 MB each (bf16)
  size_t wfc_off = (off + xg_bytes + 255) & ~(size_t)255;
  size_t wgt_off = wfc_off + wbytes;
  size_t wpj_off = wgt_off + wbytes;
  unsigned short* wfc_bf = (unsigned short*)(ws + wfc_off);
  unsigned short* wgt_bf = (unsigned short*)(ws + wgt_off);
  unsigned short* wpj_bf = (unsigned short*)(ws + wpj_off);

  size_t act_off = (wpj_off + wbytes + 255) & ~(size_t)255;
  unsigned short* act = (unsigned short*)(ws + act_off);
  size_t o_off = (act_off + R * H_DIM * 2 + 255) & ~(size_t)255;
  float* o = (float*)(ws + o_off);
  const size_t need = o_off + R * C_DIM * 4;
  if (ws_size < need || n_in < 9) return;  // scratch too small: bail cleanly

  hipMemsetAsync(ws, 0, 2048, stream);      // counts/pad_off/tables
  hipMemsetAsync(Xg, 0, xg_bytes, stream);  // zero pad rows

  const int WN4 = (int)(E_DIM * C_DIM * H_DIM / 4);
  cvt_kernel<<<4096, 256, 0, stream>>>((const float*)d_in[2], wfc_bf, WN4);
  cvt_kernel<<<4096, 256, 0, stream>>>((const float*)d_in[4], wgt_bf, WN4);
  cvt_kernel<<<4096, 256, 0, stream>>>((const float*)d_in[6], wpj_bf, WN4);

  router_kernel<<<N, 64, 0, stream>>>((const float*)d_in[0], (const float*)d_in[1],
                                      tok_e, tok_p);
  assign_kernel<<<(N + 255) / 256, 256, 0, stream>>>(tok_e, counts, tok_rank, N);
  schedule_kernel<<<1, 64, 0, stream>>>(counts, pad_off, table_e, table_row, tableCap);
  gather_kernel<<<N, 64, 0, stream>>>((const float*)d_in[0], tok_e, tok_rank, pad_off,
                                      tok_slot, Xg);
  fcgate_kernel<<<dim3(H_DIM / 64, tableCap), 256, 0, stream>>>(
      Xg, wfc_bf, (const float*)d_in[3], wgt_bf, (const float*)d_in[5],
      table_e, table_row, act);
  proj_kernel<<<dim3(C_DIM / 64, tableCap), 256, 0, stream>>>(
      act, wpj_bf, (const float*)d_in[7], table_e, table_row, o);
  combine_kernel<<<N, 64, 0, stream>>>(o, tok_slot, tok_p, (float*)d_out);
}

// Round 4
// 414.480 us; speedup vs baseline: 1.4637x; 1.0172x over previous
//
#include <hip/hip_runtime.h>
#include <hip/hip_bf16.h>
#include <cmath>

#define C_DIM 768
#define E_DIM 8
#define H_DIM 3072
#define CNT_STRIDE 32  // ints; one 128B line per expert counter

typedef short s16x8 __attribute__((ext_vector_type(8)));
typedef short s16x4 __attribute__((ext_vector_type(4)));
typedef float f32x4 __attribute__((ext_vector_type(4)));

__device__ __forceinline__ float bf2f(unsigned short u) {
  unsigned int v = ((unsigned int)u) << 16;
  float f;
  __builtin_memcpy(&f, &v, 4);
  return f;
}

__device__ __forceinline__ unsigned short f2bf(float f) {
  __hip_bfloat16 h = __float2bfloat16(f);
  unsigned short u;
  __builtin_memcpy(&u, &h, 2);
  return u;
}

// ---------------- K0: fused fp32->bf16 convert + transpose ----------------
// in: [E][R][CC] fp32 ; out: [E][CC][R] bf16. 64x64 tile. Grid (CC/64, R/64, E), block 256.
__global__ void tr_cvt_kernel(const float* __restrict__ in, unsigned short* __restrict__ out,
                              int R, int CC) {
  const int e = blockIdx.z;
  const int c0 = blockIdx.x * 64;  // CC-dim tile base
  const int r0 = blockIdx.y * 64;  // R-dim tile base
  const int tid = threadIdx.x;
  __shared__ unsigned short T[64 * 68];  // [col][row], stride 68 (16B-aligned, 2-way banks)
  const int row = tid >> 2;        // 0..63 (R-dim)
  const int cq = (tid & 3) * 4;    // col sub-base
  const float* src = in + (size_t)e * R * CC + (size_t)(r0 + row) * CC + c0;
#pragma unroll
  for (int j = 0; j < 4; ++j) {
    const int c = cq + j * 16;
    const float4 v = *(const float4*)(src + c);
    T[(c + 0) * 68 + row] = f2bf(v.x);
    T[(c + 1) * 68 + row] = f2bf(v.y);
    T[(c + 2) * 68 + row] = f2bf(v.z);
    T[(c + 3) * 68 + row] = f2bf(v.w);
  }
  __syncthreads();
  const int oc = tid >> 2;          // 0..63 (CC-dim = out row)
  const int half = (tid & 3) * 16;  // 0/16/32/48 within out row (R-dim)
  unsigned short* dst = out + (size_t)e * CC * R + (size_t)(c0 + oc) * R + r0 + half;
  *(uint4*)(dst) = *(const uint4*)(&T[oc * 68 + half]);
  *(uint4*)(dst + 8) = *(const uint4*)(&T[oc * 68 + half + 8]);
}

// ---------------- K1: router (one wave per token, fp32; NO atomics) ----------------
__global__ void router_kernel(const float* __restrict__ x,
                              const float* __restrict__ w_r,
                              int* __restrict__ tok_e,
                              float* __restrict__ tok_p) {
  const int t = blockIdx.x;
  const int lane = threadIdx.x;  // 64
  float acc[E_DIM];
#pragma unroll
  for (int e = 0; e < E_DIM; ++e) acc[e] = 0.f;
  for (int c = lane; c < C_DIM; c += 64) {
    const float xv = x[(size_t)t * C_DIM + c];
    const float4 w0 = *(const float4*)(w_r + (size_t)c * E_DIM);
    const float4 w1 = *(const float4*)(w_r + (size_t)c * E_DIM + 4);
    acc[0] += xv * w0.x; acc[1] += xv * w0.y; acc[2] += xv * w0.z; acc[3] += xv * w0.w;
    acc[4] += xv * w1.x; acc[5] += xv * w1.y; acc[6] += xv * w1.z; acc[7] += xv * w1.w;
  }
#pragma unroll
  for (int e = 0; e < E_DIM; ++e) {
#pragma unroll
    for (int off = 32; off > 0; off >>= 1) acc[e] += __shfl_xor(acc[e], off, 64);
  }
  if (lane == 0) {
    int i0 = 0;
#pragma unroll
    for (int e = 1; e < E_DIM; ++e)
      if (acc[e] > acc[i0]) i0 = e;   // strict > : lowest index on tie (matches jax top_k)
    int i1 = (i0 == 0) ? 1 : 0;
#pragma unroll
    for (int e = 0; e < E_DIM; ++e)
      if (e != i0 && acc[e] > acc[i1]) i1 = e;
    const float d = expf(acc[i1] - acc[i0]);  // <= 1
    const float p0 = 1.f / (1.f + d);
    tok_e[2 * t] = i0;
    tok_e[2 * t + 1] = i1;
    tok_p[2 * t] = p0;
    tok_p[2 * t + 1] = 1.f - p0;
  }
}

// ---------------- K1b: slot rank assignment (LDS-aggregated; 64 global atomics total) ----
__global__ void assign_kernel(const int* __restrict__ tok_e,
                              int* __restrict__ counts,     // strided CNT_STRIDE
                              int* __restrict__ tok_rank,
                              int N) {
  __shared__ int lcnt[E_DIM];
  __shared__ int lbase[E_DIM];
  const int tid = threadIdx.x;
  const int t = blockIdx.x * blockDim.x + tid;
  if (tid < E_DIM) lcnt[tid] = 0;
  __syncthreads();
  int e0 = 0, e1 = 0, r0 = 0, r1 = 0;
  const bool valid = (t < N);
  if (valid) {
    e0 = tok_e[2 * t];
    e1 = tok_e[2 * t + 1];
    r0 = atomicAdd(&lcnt[e0], 1);  // LDS atomic — on-CU, fast
    r1 = atomicAdd(&lcnt[e1], 1);
  }
  __syncthreads();
  if (tid < E_DIM) lbase[tid] = atomicAdd(counts + tid * CNT_STRIDE, lcnt[tid]);
  __syncthreads();
  if (valid) {
    tok_rank[2 * t] = lbase[e0] + r0;
    tok_rank[2 * t + 1] = lbase[e1] + r1;
  }
}

// ---------------- K2: schedule (single thread; 8 experts) ----------------
__global__ void schedule_kernel(const int* __restrict__ counts,
                                int* __restrict__ pad_off,
                                int* __restrict__ table_e,
                                int* __restrict__ table_row,
                                int tableCap) {
  if (threadIdx.x != 0) return;
  int running = 0, idx = 0;
  for (int e = 0; e < E_DIM; ++e) {
    pad_off[e] = running;
    const int tiles = (counts[e * CNT_STRIDE] + 127) >> 7;  // 128-row tiles
    for (int j = 0; j < tiles && idx < tableCap; ++j) {
      table_e[idx] = e;
      table_row[idx] = running + j * 128;
      ++idx;
    }
    running += tiles << 7;
  }
  for (; idx < tableCap; ++idx) table_e[idx] = -1;
}

// ---------------- K3: gather rows (fp32 x -> bf16 Xg; NO atomics) ----------------
__global__ void gather_kernel(const float* __restrict__ x,
                              const int* __restrict__ tok_e,
                              const int* __restrict__ tok_rank,
                              const int* __restrict__ pad_off,
                              int* __restrict__ tok_slot,
                              unsigned short* __restrict__ Xg) {
  const int t = blockIdx.x;
  const int lane = threadIdx.x;  // 64
  const int s0 = pad_off[tok_e[2 * t]] + tok_rank[2 * t];
  const int s1 = pad_off[tok_e[2 * t + 1]] + tok_rank[2 * t + 1];
  if (lane == 0) {
    tok_slot[2 * t] = s0;
    tok_slot[2 * t + 1] = s1;
  }
  const float4* src = (const float4*)(x + (size_t)t * C_DIM);  // 192 x 16B
  for (int q = lane; q < C_DIM / 4; q += 64) {
    const float4 v = src[q];
    s16x4 p;
    p[0] = (short)f2bf(v.x);
    p[1] = (short)f2bf(v.y);
    p[2] = (short)f2bf(v.z);
    p[3] = (short)f2bf(v.w);
    *(s16x4*)(Xg + (size_t)s0 * C_DIM + q * 4) = p;
    *(s16x4*)(Xg + (size_t)s1 * C_DIM + q * 4) = p;
  }
}

// ---------------- K4: fused fc + gate GEMM + SwiGLU -> act (bf16) ----------------
// Block tile 128(M) x 128(N), BK=32, B^T ([n][k]) LDS layout -> all-b128 frag reads.
// 4 waves 2x2; wave tile 64x64 = 4x4 mfma16 tiles per tensor.
__global__ __launch_bounds__(256, 2) void fcgate_kernel(
    const unsigned short* __restrict__ Xg, const unsigned short* __restrict__ wfcT,
    const float* __restrict__ b_fc, const unsigned short* __restrict__ wgtT,
    const float* __restrict__ b_gt, const int* __restrict__ table_e,
    const int* __restrict__ table_row, unsigned short* __restrict__ act) {
  const int mt = blockIdx.y;
  const int e = table_e[mt];
  if (e < 0) return;
  const int row0 = table_row[mt];
  const int nt = blockIdx.x;  // 0..23 (H/128)
  const int tid = threadIdx.x;
  const int lane = tid & 63;
  const int wid = tid >> 6;
  const int quad = lane >> 4;
  const int l16 = lane & 15;
  const int wrow = (wid >> 1) * 64;  // 0/64
  const int wcol = (wid & 1) * 64;   // 0/64

  __shared__ unsigned short As[128 * 40];   // [m][k]
  __shared__ unsigned short BsF[128 * 40];  // [n][k] (B^T)
  __shared__ unsigned short BsG[128 * 40];

  const unsigned short* pF = wfcT + (size_t)e * H_DIM * C_DIM + (size_t)(nt * 128) * C_DIM;
  const unsigned short* pG = wgtT + (size_t)e * H_DIM * C_DIM + (size_t)(nt * 128) * C_DIM;

  f32x4 accH[4][4], accG[4][4];
#pragma unroll
  for (int i = 0; i < 4; ++i)
#pragma unroll
    for (int j = 0; j < 4; ++j)
#pragma unroll
      for (int r = 0; r < 4; ++r) {
        accH[i][j][r] = 0.f;
        accG[i][j][r] = 0.f;
      }

  const int sr = tid >> 1;        // 0..127 (row for A and B^T tiles)
  const int sc = (tid & 1) * 16;  // 0/16

  for (int k0 = 0; k0 < C_DIM; k0 += 32) {
    const uint4 av0 = *(const uint4*)(Xg + (size_t)(row0 + sr) * C_DIM + k0 + sc);
    const uint4 av1 = *(const uint4*)(Xg + (size_t)(row0 + sr) * C_DIM + k0 + sc + 8);
    const uint4 bf0 = *(const uint4*)(pF + (size_t)sr * C_DIM + k0 + sc);
    const uint4 bf1 = *(const uint4*)(pF + (size_t)sr * C_DIM + k0 + sc + 8);
    const uint4 bg0 = *(const uint4*)(pG + (size_t)sr * C_DIM + k0 + sc);
    const uint4 bg1 = *(const uint4*)(pG + (size_t)sr * C_DIM + k0 + sc + 8);
    __syncthreads();
    *(uint4*)(&As[sr * 40 + sc]) = av0;
    *(uint4*)(&As[sr * 40 + sc + 8]) = av1;
    *(uint4*)(&BsF[sr * 40 + sc]) = bf0;
    *(uint4*)(&BsF[sr * 40 + sc + 8]) = bf1;
    *(uint4*)(&BsG[sr * 40 + sc]) = bg0;
    *(uint4*)(&BsG[sr * 40 + sc + 8]) = bg1;
    __syncthreads();

    s16x8 a[4], bF[4], bG[4];
#pragma unroll
    for (int tr = 0; tr < 4; ++tr)
      a[tr] = *(const s16x8*)(&As[(wrow + tr * 16 + l16) * 40 + quad * 8]);
#pragma unroll
    for (int tc = 0; tc < 4; ++tc)
      bF[tc] = *(const s16x8*)(&BsF[(wcol + tc * 16 + l16) * 40 + quad * 8]);
#pragma unroll
    for (int tc = 0; tc < 4; ++tc)
      bG[tc] = *(const s16x8*)(&BsG[(wcol + tc * 16 + l16) * 40 + quad * 8]);

#pragma unroll
    for (int tr = 0; tr < 4; ++tr)
#pragma unroll
      for (int tc = 0; tc < 4; ++tc) {
        accH[tr][tc] = __builtin_amdgcn_mfma_f32_16x16x32_bf16(a[tr], bF[tc], accH[tr][tc], 0, 0, 0);
        accG[tr][tc] = __builtin_amdgcn_mfma_f32_16x16x32_bf16(a[tr], bG[tc], accG[tr][tc], 0, 0, 0);
      }
  }

  // epilogue: act = (h + b_fc) * silu(g + b_gt)
#pragma unroll
  for (int tc = 0; tc < 4; ++tc) {
    const int col = nt * 128 + wcol + tc * 16 + l16;
    const float bf = b_fc[e * H_DIM + col];
    const float bg = b_gt[e * H_DIM + col];
#pragma unroll
    for (int tr = 0; tr < 4; ++tr) {
#pragma unroll
      for (int r = 0; r < 4; ++r) {
        const int row = row0 + wrow + tr * 16 + quad * 4 + r;  // C/D: row=quad*4+reg, col=l16
        const float hv = accH[tr][tc][r] + bf;
        const float gv = accG[tr][tc][r] + bg;
        const float sv = gv / (1.f + __expf(-gv));
        act[(size_t)row * H_DIM + col] = f2bf(hv * sv);
      }
    }
  }
}

// ---------------- K5: proj GEMM -> o (fp32); B^T ([c][h]) layout ----------------
// Block tile 128(M) x 64(N), BK=32. 4 waves 2x2; wave tile 64x32.
__global__ __launch_bounds__(256, 2) void proj_kernel(
    const unsigned short* __restrict__ act, const unsigned short* __restrict__ wpjT,
    const float* __restrict__ b_pj, const int* __restrict__ table_e,
    const int* __restrict__ table_row, float* __restrict__ o) {
  const int mt = blockIdx.y;
  const int e = table_e[mt];
  if (e < 0) return;
  const int row0 = table_row[mt];
  const int nt = blockIdx.x;  // 0..11 (C/64)
  const int tid = threadIdx.x;
  const int lane = tid & 63;
  const int wid = tid >> 6;
  const int quad = lane >> 4;
  const int l16 = lane & 15;
  const int wrow = (wid >> 1) * 64;
  const int wcol = (wid & 1) * 32;

  __shared__ unsigned short As[128 * 40];  // [m][k]
  __shared__ unsigned short Bs[64 * 40];   // [n][k] (B^T)

  const unsigned short* pB = wpjT + (size_t)e * C_DIM * H_DIM + (size_t)(nt * 64) * H_DIM;

  f32x4 acc[4][2];
#pragma unroll
  for (int i = 0; i < 4; ++i)
#pragma unroll
    for (int j = 0; j < 2; ++j)
#pragma unroll
      for (int r = 0; r < 4; ++r) acc[i][j][r] = 0.f;

  const int sr = tid >> 1;        // 0..127
  const int sc = (tid & 1) * 16;  // 0/16
  const int br = tid >> 2;        // 0..63
  const int bc = (tid & 3) * 8;   // 0..24

  for (int k0 = 0; k0 < H_DIM; k0 += 32) {
    const uint4 av0 = *(const uint4*)(act + (size_t)(row0 + sr) * H_DIM + k0 + sc);
    const uint4 av1 = *(const uint4*)(act + (size_t)(row0 + sr) * H_DIM + k0 + sc + 8);
    const uint4 bv = *(const uint4*)(pB + (size_t)br * H_DIM + k0 + bc);
    __syncthreads();
    *(uint4*)(&As[sr * 40 + sc]) = av0;
    *(uint4*)(&As[sr * 40 + sc + 8]) = av1;
    *(uint4*)(&Bs[br * 40 + bc]) = bv;
    __syncthreads();

    s16x8 a[4], bB[2];
#pragma unroll
    for (int tr = 0; tr < 4; ++tr)
      a[tr] = *(const s16x8*)(&As[(wrow + tr * 16 + l16) * 40 + quad * 8]);
#pragma unroll
    for (int tc = 0; tc < 2; ++tc)
      bB[tc] = *(const s16x8*)(&Bs[(wcol + tc * 16 + l16) * 40 + quad * 8]);

#pragma unroll
    for (int tr = 0; tr < 4; ++tr)
#pragma unroll
      for (int tc = 0; tc < 2; ++tc)
        acc[tr][tc] = __builtin_amdgcn_mfma_f32_16x16x32_bf16(a[tr], bB[tc], acc[tr][tc], 0, 0, 0);
  }

#pragma unroll
  for (int tc = 0; tc < 2; ++tc) {
    const int col = nt * 64 + wcol + tc * 16 + l16;
    const float bp = b_pj[e * C_DIM + col];
#pragma unroll
    for (int tr = 0; tr < 4; ++tr) {
#pragma unroll
      for (int r = 0; r < 4; ++r) {
        const int row = row0 + wrow + tr * 16 + quad * 4 + r;
        o[(size_t)row * C_DIM + col] = acc[tr][tc][r] + bp;
      }
    }
  }
}

// ---------------- K6: combine -> fp32 out ----------------
__global__ void combine_kernel(const float* __restrict__ o,
                               const int* __restrict__ tok_slot,
                               const float* __restrict__ tok_p,
                               float* __restrict__ out) {
  const int t = blockIdx.x;
  const int lane = threadIdx.x;  // 64
  const int s0 = tok_slot[2 * t], s1 = tok_slot[2 * t + 1];
  const float p0 = tok_p[2 * t], p1 = tok_p[2 * t + 1];
  const f32x4* r0 = (const f32x4*)(o + (size_t)s0 * C_DIM);
  const f32x4* r1 = (const f32x4*)(o + (size_t)s1 * C_DIM);
  f32x4* dst = (f32x4*)(out + (size_t)t * C_DIM);
  for (int q = lane; q < C_DIM / 4; q += 64) {
    const f32x4 a = r0[q];
    const f32x4 b = r1[q];
    dst[q] = a * p0 + b * p1;
  }
}

extern "C" void kernel_launch(void* const* d_in, const int* in_sizes, int n_in,
                              void* d_out, int out_size, void* d_ws, size_t ws_size,
                              hipStream_t stream) {
  const int N = in_sizes[0] / C_DIM;  // 2048 tokens
  char* ws = (char*)d_ws;

  int* counts = (int*)(ws + 0);       // 8 x CNT_STRIDE ints = 1024 B
  int* pad_off = (int*)(ws + 1024);   // 8 ints
  int* table_e = (int*)(ws + 1152);   // up to 64
  int* table_row = (int*)(ws + 1408);
  int* tok_e = (int*)(ws + 2048);
  float* tok_p = (float*)(ws + 2048 + (size_t)8 * N);
  int* tok_rank = (int*)(ws + 2048 + (size_t)16 * N);
  int* tok_slot = (int*)(ws + 2048 + (size_t)24 * N);

  int tableCap = (2 * N) / 128 + E_DIM;  // 40 for N=2048 (>= max possible tiles)
  if (tableCap > 64) tableCap = 64;

  size_t off = 2048 + (size_t)32 * N;
  off = (off + 255) & ~(size_t)255;
  const size_t R = (size_t)2 * N + 128 * E_DIM;  // padded-row allocation (5120)
  unsigned short* Xg = (unsigned short*)(ws + off);
  const size_t xg_bytes = R * C_DIM * 2;

  const size_t wbytes = (size_t)E_DIM * C_DIM * H_DIM * 2;  // 37.75 MB each (bf16)
  size_t wfc_off = (off + xg_bytes + 255) & ~(size_t)255;
  size_t wgt_off = wfc_off + wbytes;
  size_t wpj_off = wgt_off + wbytes;
  unsigned short* wfcT = (unsigned short*)(ws + wfc_off);  // [e][h][c]
  unsigned short* wgtT = (unsigned short*)(ws + wgt_off);  // [e][h][c]
  unsigned short* wpjT = (unsigned short*)(ws + wpj_off);  // [e][c][h]

  size_t act_off = (wpj_off + wbytes + 255) & ~(size_t)255;
  unsigned short* act = (unsigned short*)(ws + act_off);
  size_t o_off = (act_off + R * H_DIM * 2 + 255) & ~(size_t)255;
  float* o = (float*)(ws + o_off);
  const size_t need = o_off + R * C_DIM * 4;
  if (ws_size < need || n_in < 9) return;  // scratch too small: bail cleanly

  hipMemsetAsync(ws, 0, 2048, stream);      // counts/pad_off/tables
  hipMemsetAsync(Xg, 0, xg_bytes, stream);  // zero pad rows

  // weights: in [E][C][H] -> out [E][H][C] (fc, gate); in [E][H][C] -> out [E][C][H] (proj)
  tr_cvt_kernel<<<dim3(H_DIM / 64, C_DIM / 64, E_DIM), 256, 0, stream>>>(
      (const float*)d_in[2], wfcT, C_DIM, H_DIM);
  tr_cvt_kernel<<<dim3(H_DIM / 64, C_DIM / 64, E_DIM), 256, 0, stream>>>(
      (const float*)d_in[4], wgtT, C_DIM, H_DIM);
  tr_cvt_kernel<<<dim3(C_DIM / 64, H_DIM / 64, E_DIM), 256, 0, stream>>>(
      (const float*)d_in[6], wpjT, H_DIM, C_DIM);

  router_kernel<<<N, 64, 0, stream>>>((const float*)d_in[0], (const float*)d_in[1],
                                      tok_e, tok_p);
  assign_kernel<<<(N + 255) / 256, 256, 0, stream>>>(tok_e, counts, tok_rank, N);
  schedule_kernel<<<1, 64, 0, stream>>>(counts, pad_off, table_e, table_row, tableCap);
  gather_kernel<<<N, 64, 0, stream>>>((const float*)d_in[0], tok_e, tok_rank, pad_off,
                                      tok_slot, Xg);
  fcgate_kernel<<<dim3(H_DIM / 128, tableCap), 256, 0, stream>>>(
      Xg, wfcT, (const float*)d_in[3], wgtT, (const float*)d_in[5],
      table_e, table_row, act);
  proj_kernel<<<dim3(C_DIM / 64, tableCap), 256, 0, stream>>>(
      act, wpjT, (const float*)d_in[7], table_e, table_row, o);
  combine_kernel<<<N, 64, 0, stream>>>(o, tok_slot, tok_p, (float*)d_out);
}

// Round 5
// 391.328 us; speedup vs baseline: 1.5503x; 1.0592x over previous
//
#include <hip/hip_runtime.h>
#include <hip/hip_bf16.h>
#include <cmath>

#define C_DIM 768
#define E_DIM 8
#define H_DIM 3072
#define CNT_STRIDE 32  // ints; one 128B line per expert counter

typedef short s16x8 __attribute__((ext_vector_type(8)));
typedef short s16x4 __attribute__((ext_vector_type(4)));
typedef float f32x4 __attribute__((ext_vector_type(4)));

__device__ __forceinline__ float bf2f(unsigned short u) {
  unsigned int v = ((unsigned int)u) << 16;
  float f;
  __builtin_memcpy(&f, &v, 4);
  return f;
}

__device__ __forceinline__ unsigned short f2bf(float f) {
  __hip_bfloat16 h = __float2bfloat16(f);
  unsigned short u;
  __builtin_memcpy(&u, &h, 2);
  return u;
}

// async global->LDS DMA, 16B per lane; LDS dest = wave-uniform base + lane*16
__device__ __forceinline__ void gll16(const unsigned short* g, unsigned short* l) {
  __builtin_amdgcn_global_load_lds(
      (const __attribute__((address_space(1))) void*)g,
      (__attribute__((address_space(3))) void*)l, 16, 0, 0);
}

// ---------------- K0: fused fp32->bf16 convert + transpose ----------------
__global__ void tr_cvt_kernel(const float* __restrict__ in, unsigned short* __restrict__ out,
                              int R, int CC) {
  const int e = blockIdx.z;
  const int c0 = blockIdx.x * 64;
  const int r0 = blockIdx.y * 64;
  const int tid = threadIdx.x;
  __shared__ unsigned short T[64 * 68];
  const int row = tid >> 2;
  const int cq = (tid & 3) * 4;
  const float* src = in + (size_t)e * R * CC + (size_t)(r0 + row) * CC + c0;
#pragma unroll
  for (int j = 0; j < 4; ++j) {
    const int c = cq + j * 16;
    const float4 v = *(const float4*)(src + c);
    T[(c + 0) * 68 + row] = f2bf(v.x);
    T[(c + 1) * 68 + row] = f2bf(v.y);
    T[(c + 2) * 68 + row] = f2bf(v.z);
    T[(c + 3) * 68 + row] = f2bf(v.w);
  }
  __syncthreads();
  const int oc = tid >> 2;
  const int half = (tid & 3) * 16;
  unsigned short* dst = out + (size_t)e * CC * R + (size_t)(c0 + oc) * R + r0 + half;
  *(uint4*)(dst) = *(const uint4*)(&T[oc * 68 + half]);
  *(uint4*)(dst + 8) = *(const uint4*)(&T[oc * 68 + half + 8]);
}

// ---------------- K1: router ----------------
__global__ void router_kernel(const float* __restrict__ x,
                              const float* __restrict__ w_r,
                              int* __restrict__ tok_e,
                              float* __restrict__ tok_p) {
  const int t = blockIdx.x;
  const int lane = threadIdx.x;
  float acc[E_DIM];
#pragma unroll
  for (int e = 0; e < E_DIM; ++e) acc[e] = 0.f;
  for (int c = lane; c < C_DIM; c += 64) {
    const float xv = x[(size_t)t * C_DIM + c];
    const float4 w0 = *(const float4*)(w_r + (size_t)c * E_DIM);
    const float4 w1 = *(const float4*)(w_r + (size_t)c * E_DIM + 4);
    acc[0] += xv * w0.x; acc[1] += xv * w0.y; acc[2] += xv * w0.z; acc[3] += xv * w0.w;
    acc[4] += xv * w1.x; acc[5] += xv * w1.y; acc[6] += xv * w1.z; acc[7] += xv * w1.w;
  }
#pragma unroll
  for (int e = 0; e < E_DIM; ++e) {
#pragma unroll
    for (int off = 32; off > 0; off >>= 1) acc[e] += __shfl_xor(acc[e], off, 64);
  }
  if (lane == 0) {
    int i0 = 0;
#pragma unroll
    for (int e = 1; e < E_DIM; ++e)
      if (acc[e] > acc[i0]) i0 = e;
    int i1 = (i0 == 0) ? 1 : 0;
#pragma unroll
    for (int e = 0; e < E_DIM; ++e)
      if (e != i0 && acc[e] > acc[i1]) i1 = e;
    const float d = expf(acc[i1] - acc[i0]);
    const float p0 = 1.f / (1.f + d);
    tok_e[2 * t] = i0;
    tok_e[2 * t + 1] = i1;
    tok_p[2 * t] = p0;
    tok_p[2 * t + 1] = 1.f - p0;
  }
}

// ---------------- K1b: slot rank assignment ----------------
__global__ void assign_kernel(const int* __restrict__ tok_e,
                              int* __restrict__ counts,
                              int* __restrict__ tok_rank,
                              int N) {
  __shared__ int lcnt[E_DIM];
  __shared__ int lbase[E_DIM];
  const int tid = threadIdx.x;
  const int t = blockIdx.x * blockDim.x + tid;
  if (tid < E_DIM) lcnt[tid] = 0;
  __syncthreads();
  int e0 = 0, e1 = 0, r0 = 0, r1 = 0;
  const bool valid = (t < N);
  if (valid) {
    e0 = tok_e[2 * t];
    e1 = tok_e[2 * t + 1];
    r0 = atomicAdd(&lcnt[e0], 1);
    r1 = atomicAdd(&lcnt[e1], 1);
  }
  __syncthreads();
  if (tid < E_DIM) lbase[tid] = atomicAdd(counts + tid * CNT_STRIDE, lcnt[tid]);
  __syncthreads();
  if (valid) {
    tok_rank[2 * t] = lbase[e0] + r0;
    tok_rank[2 * t + 1] = lbase[e1] + r1;
  }
}

// ---------------- K2: schedule ----------------
__global__ void schedule_kernel(const int* __restrict__ counts,
                                int* __restrict__ pad_off,
                                int* __restrict__ table_e,
                                int* __restrict__ table_row,
                                int tableCap) {
  if (threadIdx.x != 0) return;
  int running = 0, idx = 0;
  for (int e = 0; e < E_DIM; ++e) {
    pad_off[e] = running;
    const int tiles = (counts[e * CNT_STRIDE] + 127) >> 7;
    for (int j = 0; j < tiles && idx < tableCap; ++j) {
      table_e[idx] = e;
      table_row[idx] = running + j * 128;
      ++idx;
    }
    running += tiles << 7;
  }
  for (; idx < tableCap; ++idx) table_e[idx] = -1;
}

// ---------------- K3: gather rows ----------------
__global__ void gather_kernel(const float* __restrict__ x,
                              const int* __restrict__ tok_e,
                              const int* __restrict__ tok_rank,
                              const int* __restrict__ pad_off,
                              int* __restrict__ tok_slot,
                              unsigned short* __restrict__ Xg) {
  const int t = blockIdx.x;
  const int lane = threadIdx.x;
  const int s0 = pad_off[tok_e[2 * t]] + tok_rank[2 * t];
  const int s1 = pad_off[tok_e[2 * t + 1]] + tok_rank[2 * t + 1];
  if (lane == 0) {
    tok_slot[2 * t] = s0;
    tok_slot[2 * t + 1] = s1;
  }
  const float4* src = (const float4*)(x + (size_t)t * C_DIM);
  for (int q = lane; q < C_DIM / 4; q += 64) {
    const float4 v = src[q];
    s16x4 p;
    p[0] = (short)f2bf(v.x);
    p[1] = (short)f2bf(v.y);
    p[2] = (short)f2bf(v.z);
    p[3] = (short)f2bf(v.w);
    *(s16x4*)(Xg + (size_t)s0 * C_DIM + q * 4) = p;
    *(s16x4*)(Xg + (size_t)s1 * C_DIM + q * 4) = p;
  }
}

// ---------------- K4: fused fc+gate GEMM + SwiGLU, async dbuf pipeline ----------------
// Block 128x128, BK=32. LDS rows unpadded 32 shorts (64B) -> DMA-compatible, conflict-free.
__global__ __launch_bounds__(256, 2) void fcgate_kernel(
    const unsigned short* __restrict__ Xg, const unsigned short* __restrict__ wfcT,
    const float* __restrict__ b_fc, const unsigned short* __restrict__ wgtT,
    const float* __restrict__ b_gt, const int* __restrict__ table_e,
    const int* __restrict__ table_row, unsigned short* __restrict__ act) {
  const int mt = blockIdx.y;
  const int e = table_e[mt];
  if (e < 0) return;
  const int row0 = table_row[mt];
  const int nt = blockIdx.x;  // 0..23
  const int tid = threadIdx.x;
  const int lane = tid & 63;
  const int wid = tid >> 6;
  const int quad = lane >> 4;
  const int l16 = lane & 15;
  const int wrow = (wid >> 1) * 64;
  const int wcol = (wid & 1) * 64;

  // per buf: As[128*32] BsF[128*32] BsG[128*32] shorts = 24KB; x2 = 48KB
  __shared__ __align__(16) unsigned short L[2][3 * 4096];

  // staging: wave wid covers rows [wid*32, wid*32+32) of each 128-row tile
  const int srow = wid * 32 + (lane >> 2);
  const int scol = (lane & 3) * 8;
  const unsigned short* gA = Xg + (size_t)(row0 + srow) * C_DIM + scol;
  const unsigned short* gF = wfcT + (size_t)e * H_DIM * C_DIM + (size_t)(nt * 128 + srow) * C_DIM + scol;
  const unsigned short* gG = wgtT + (size_t)e * H_DIM * C_DIM + (size_t)(nt * 128 + srow) * C_DIM + scol;
  const int ldsOff = wid * 1024;  // shorts

  f32x4 accH[4][4], accG[4][4];
#pragma unroll
  for (int i = 0; i < 4; ++i)
#pragma unroll
    for (int j = 0; j < 4; ++j)
#pragma unroll
      for (int r = 0; r < 4; ++r) {
        accH[i][j][r] = 0.f;
        accG[i][j][r] = 0.f;
      }

  auto stage = [&](int buf, int k0) {
    unsigned short* As = &L[buf][0];
    unsigned short* BF = &L[buf][4096];
    unsigned short* BG = &L[buf][8192];
    gll16(gA + k0, As + ldsOff);
    gll16(gA + 16 * C_DIM + k0, As + ldsOff + 512);
    gll16(gF + k0, BF + ldsOff);
    gll16(gF + 16 * C_DIM + k0, BF + ldsOff + 512);
    gll16(gG + k0, BG + ldsOff);
    gll16(gG + 16 * C_DIM + k0, BG + ldsOff + 512);
  };

  auto compute = [&](int buf) {
    const unsigned short* As = &L[buf][0];
    const unsigned short* BF = &L[buf][4096];
    const unsigned short* BG = &L[buf][8192];
    s16x8 a[4], bF[4], bG[4];
#pragma unroll
    for (int tr = 0; tr < 4; ++tr)
      a[tr] = *(const s16x8*)(As + (wrow + tr * 16 + l16) * 32 + quad * 8);
#pragma unroll
    for (int tc = 0; tc < 4; ++tc)
      bF[tc] = *(const s16x8*)(BF + (wcol + tc * 16 + l16) * 32 + quad * 8);
#pragma unroll
    for (int tc = 0; tc < 4; ++tc)
      bG[tc] = *(const s16x8*)(BG + (wcol + tc * 16 + l16) * 32 + quad * 8);
#pragma unroll
    for (int tr = 0; tr < 4; ++tr)
#pragma unroll
      for (int tc = 0; tc < 4; ++tc) {
        accH[tr][tc] = __builtin_amdgcn_mfma_f32_16x16x32_bf16(a[tr], bF[tc], accH[tr][tc], 0, 0, 0);
        accG[tr][tc] = __builtin_amdgcn_mfma_f32_16x16x32_bf16(a[tr], bG[tc], accG[tr][tc], 0, 0, 0);
      }
  };

  stage(0, 0);
  int buf = 0;
  for (int i = 0; i < 23; ++i) {  // 24 K-iters total (768/32)
    stage(buf ^ 1, (i + 1) * 32);
    asm volatile("s_waitcnt vmcnt(6)" ::: "memory");  // current buf's 6 DMAs done
    __builtin_amdgcn_s_barrier();
    asm volatile("" ::: "memory");
    compute(buf);
    asm volatile("" ::: "memory");
    __builtin_amdgcn_s_barrier();  // all waves done reading before next overwrite
    asm volatile("" ::: "memory");
    buf ^= 1;
  }
  asm volatile("s_waitcnt vmcnt(0)" ::: "memory");
  __builtin_amdgcn_s_barrier();
  asm volatile("" ::: "memory");
  compute(buf);

  // epilogue: act = (h + b_fc) * silu(g + b_gt)
#pragma unroll
  for (int tc = 0; tc < 4; ++tc) {
    const int col = nt * 128 + wcol + tc * 16 + l16;
    const float bf = b_fc[e * H_DIM + col];
    const float bg = b_gt[e * H_DIM + col];
#pragma unroll
    for (int tr = 0; tr < 4; ++tr) {
#pragma unroll
      for (int r = 0; r < 4; ++r) {
        const int row = row0 + wrow + tr * 16 + quad * 4 + r;
        const float hv = accH[tr][tc][r] + bf;
        const float gv = accG[tr][tc][r] + bg;
        const float sv = gv / (1.f + __expf(-gv));
        act[(size_t)row * H_DIM + col] = f2bf(hv * sv);
      }
    }
  }
}

// ---------------- K5: proj GEMM -> o (fp32), async dbuf pipeline ----------------
// Block 128x64, BK=32; wave tile 64x32.
__global__ __launch_bounds__(256, 4) void proj_kernel(
    const unsigned short* __restrict__ act, const unsigned short* __restrict__ wpjT,
    const float* __restrict__ b_pj, const int* __restrict__ table_e,
    const int* __restrict__ table_row, float* __restrict__ o) {
  const int mt = blockIdx.y;
  const int e = table_e[mt];
  if (e < 0) return;
  const int row0 = table_row[mt];
  const int nt = blockIdx.x;  // 0..11
  const int tid = threadIdx.x;
  const int lane = tid & 63;
  const int wid = tid >> 6;
  const int quad = lane >> 4;
  const int l16 = lane & 15;
  const int wrow = (wid >> 1) * 64;
  const int wcol = (wid & 1) * 32;

  // per buf: As[128*32] + Bs[64*32] shorts = 12KB; x2 = 24KB
  __shared__ __align__(16) unsigned short L[2][4096 + 2048];

  const int srowA = wid * 32 + (lane >> 2);
  const int srowB = wid * 16 + (lane >> 2);
  const int scol = (lane & 3) * 8;
  const unsigned short* gA = act + (size_t)(row0 + srowA) * H_DIM + scol;
  const unsigned short* gB = wpjT + (size_t)e * C_DIM * H_DIM + (size_t)(nt * 64 + srowB) * H_DIM + scol;

  f32x4 acc[4][2];
#pragma unroll
  for (int i = 0; i < 4; ++i)
#pragma unroll
    for (int j = 0; j < 2; ++j)
#pragma unroll
      for (int r = 0; r < 4; ++r) acc[i][j][r] = 0.f;

  auto stage = [&](int buf, int k0) {
    unsigned short* As = &L[buf][0];
    unsigned short* Bs = &L[buf][4096];
    gll16(gA + k0, As + wid * 1024);
    gll16(gA + 16 * H_DIM + k0, As + wid * 1024 + 512);
    gll16(gB + k0, Bs + wid * 512);
  };

  auto compute = [&](int buf) {
    const unsigned short* As = &L[buf][0];
    const unsigned short* Bs = &L[buf][4096];
    s16x8 a[4], bB[2];
#pragma unroll
    for (int tr = 0; tr < 4; ++tr)
      a[tr] = *(const s16x8*)(As + (wrow + tr * 16 + l16) * 32 + quad * 8);
#pragma unroll
    for (int tc = 0; tc < 2; ++tc)
      bB[tc] = *(const s16x8*)(Bs + (wcol + tc * 16 + l16) * 32 + quad * 8);
#pragma unroll
    for (int tr = 0; tr < 4; ++tr)
#pragma unroll
      for (int tc = 0; tc < 2; ++tc)
        acc[tr][tc] = __builtin_amdgcn_mfma_f32_16x16x32_bf16(a[tr], bB[tc], acc[tr][tc], 0, 0, 0);
  };

  stage(0, 0);
  int buf = 0;
  for (int i = 0; i < 95; ++i) {  // 96 K-iters (3072/32)
    stage(buf ^ 1, (i + 1) * 32);
    asm volatile("s_waitcnt vmcnt(3)" ::: "memory");
    __builtin_amdgcn_s_barrier();
    asm volatile("" ::: "memory");
    compute(buf);
    asm volatile("" ::: "memory");
    __builtin_amdgcn_s_barrier();
    asm volatile("" ::: "memory");
    buf ^= 1;
  }
  asm volatile("s_waitcnt vmcnt(0)" ::: "memory");
  __builtin_amdgcn_s_barrier();
  asm volatile("" ::: "memory");
  compute(buf);

#pragma unroll
  for (int tc = 0; tc < 2; ++tc) {
    const int col = nt * 64 + wcol + tc * 16 + l16;
    const float bp = b_pj[e * C_DIM + col];
#pragma unroll
    for (int tr = 0; tr < 4; ++tr) {
#pragma unroll
      for (int r = 0; r < 4; ++r) {
        const int row = row0 + wrow + tr * 16 + quad * 4 + r;
        o[(size_t)row * C_DIM + col] = acc[tr][tc][r] + bp;
      }
    }
  }
}

// ---------------- K6: combine -> fp32 out ----------------
__global__ void combine_kernel(const float* __restrict__ o,
                               const int* __restrict__ tok_slot,
                               const float* __restrict__ tok_p,
                               float* __restrict__ out) {
  const int t = blockIdx.x;
  const int lane = threadIdx.x;
  const int s0 = tok_slot[2 * t], s1 = tok_slot[2 * t + 1];
  const float p0 = tok_p[2 * t], p1 = tok_p[2 * t + 1];
  const f32x4* r0 = (const f32x4*)(o + (size_t)s0 * C_DIM);
  const f32x4* r1 = (const f32x4*)(o + (size_t)s1 * C_DIM);
  f32x4* dst = (f32x4*)(out + (size_t)t * C_DIM);
  for (int q = lane; q < C_DIM / 4; q += 64) {
    const f32x4 a = r0[q];
    const f32x4 b = r1[q];
    dst[q] = a * p0 + b * p1;
  }
}

extern "C" void kernel_launch(void* const* d_in, const int* in_sizes, int n_in,
                              void* d_out, int out_size, void* d_ws, size_t ws_size,
                              hipStream_t stream) {
  const int N = in_sizes[0] / C_DIM;  // 2048 tokens
  char* ws = (char*)d_ws;

  int* counts = (int*)(ws + 0);
  int* pad_off = (int*)(ws + 1024);
  int* table_e = (int*)(ws + 1152);
  int* table_row = (int*)(ws + 1408);
  int* tok_e = (int*)(ws + 2048);
  float* tok_p = (float*)(ws + 2048 + (size_t)8 * N);
  int* tok_rank = (int*)(ws + 2048 + (size_t)16 * N);
  int* tok_slot = (int*)(ws + 2048 + (size_t)24 * N);

  int tableCap = (2 * N) / 128 + E_DIM;
  if (tableCap > 64) tableCap = 64;

  size_t off = 2048 + (size_t)32 * N;
  off = (off + 255) & ~(size_t)255;
  const size_t R = (size_t)2 * N + 128 * E_DIM;  // 5120 padded rows
  unsigned short* Xg = (unsigned short*)(ws + off);
  const size_t xg_bytes = R * C_DIM * 2;

  const size_t wbytes = (size_t)E_DIM * C_DIM * H_DIM * 2;
  size_t wfc_off = (off + xg_bytes + 255) & ~(size_t)255;
  size_t wgt_off = wfc_off + wbytes;
  size_t wpj_off = wgt_off + wbytes;
  unsigned short* wfcT = (unsigned short*)(ws + wfc_off);  // [e][h][c]
  unsigned short* wgtT = (unsigned short*)(ws + wgt_off);  // [e][h][c]
  unsigned short* wpjT = (unsigned short*)(ws + wpj_off);  // [e][c][h]

  size_t act_off = (wpj_off + wbytes + 255) & ~(size_t)255;
  unsigned short* act = (unsigned short*)(ws + act_off);
  size_t o_off = (act_off + R * H_DIM * 2 + 255) & ~(size_t)255;
  float* o = (float*)(ws + o_off);
  const size_t need = o_off + R * C_DIM * 4;
  if (ws_size < need || n_in < 9) return;

  hipMemsetAsync(ws, 0, 2048, stream);
  hipMemsetAsync(Xg, 0, xg_bytes, stream);

  tr_cvt_kernel<<<dim3(H_DIM / 64, C_DIM / 64, E_DIM), 256, 0, stream>>>(
      (const float*)d_in[2], wfcT, C_DIM, H_DIM);
  tr_cvt_kernel<<<dim3(H_DIM / 64, C_DIM / 64, E_DIM), 256, 0, stream>>>(
      (const float*)d_in[4], wgtT, C_DIM, H_DIM);
  tr_cvt_kernel<<<dim3(C_DIM / 64, H_DIM / 64, E_DIM), 256, 0, stream>>>(
      (const float*)d_in[6], wpjT, H_DIM, C_DIM);

  router_kernel<<<N, 64, 0, stream>>>((const float*)d_in[0], (const float*)d_in[1],
                                      tok_e, tok_p);
  assign_kernel<<<(N + 255) / 256, 256, 0, stream>>>(tok_e, counts, tok_rank, N);
  schedule_kernel<<<1, 64, 0, stream>>>(counts, pad_off, table_e, table_row, tableCap);
  gather_kernel<<<N, 64, 0, stream>>>((const float*)d_in[0], tok_e, tok_rank, pad_off,
                                      tok_slot, Xg);
  fcgate_kernel<<<dim3(H_DIM / 128, tableCap), 256, 0, stream>>>(
      Xg, wfcT, (const float*)d_in[3], wgtT, (const float*)d_in[5],
      table_e, table_row, act);
  proj_kernel<<<dim3(C_DIM / 64, tableCap), 256, 0, stream>>>(
      act, wpjT, (const float*)d_in[7], table_e, table_row, o);
  combine_kernel<<<N, 64, 0, stream>>>(o, tok_slot, tok_p, (float*)d_out);
}